// Round 17
// baseline (253.017 us; speedup 1.0000x reference)
//
#include <hip/hip_runtime.h>

#define SS 512
#define NPARTS 11
#define NB 4
#define FEAT (9*126*126)   // 142884

// ws layout (floats)
#define H1SZ (4*7*254*254)       // 1806448
#define OFF_H1 0
#define OFF_PART (OFF_H1 + H1SZ)      // partials [4][64][32] = 8192

// ---------------- conv1 (5x5, 4->7) + relu + maxpool2 ----------------
// INSTRUMENTATION: gridDim.z=4 -> 4 identical z-slices (duplicate writes).
// Marginal slope => throughput component; dispatch (~160-220us) crosses the
// rocprof top-5 threshold so conv1's counters finally become visible.
__global__ __launch_bounds__(256) void conv1_kernel(
    const float4* __restrict__ x4,
    const float* __restrict__ w,      // [7][4][5][5]
    const float* __restrict__ bias,   // [7]
    float* __restrict__ h1) {
  __shared__ float4 wlds[175];        // [tap 25][k 7], float4 over c
  int tid = threadIdx.x;
  {
    float* wf = (float*)wlds;
    for (int i = tid; i < 700; i += 256) {
      int tap = i / 28, r = i % 28;
      int k = r >> 2, c = r & 3;
      int dy = tap / 5, dx = tap % 5;
      wf[i] = w[((k * 4 + c) * 5 + dy) * 5 + dx];
    }
  }
  __syncthreads();

  int b = blockIdx.y;
  int by = blockIdx.x >> 4, bx = blockIdx.x & 15;
  int ty = tid >> 4, tx = tid & 15;
  int py = by * 16 + ty, px = bx * 16 + tx;
  if (py >= 254 || px >= 254) return;

  const float4* img = x4 + (size_t)b * 6144 * 512 + (size_t)(2 * py) * 512 + 2 * px;

  float acc[4][7];
#pragma unroll
  for (int p = 0; p < 4; p++)
#pragma unroll
    for (int k = 0; k < 7; k++) acc[p][k] = bias[k];

#pragma unroll 1
  for (int dy = 0; dy < 5; dy++) {
    const float4* r0 = img + dy * 512;
    const float4* r1 = r0 + 512;
    float4 a0[6], a1[6];
#pragma unroll
    for (int j = 0; j < 6; j++) { a0[j] = r0[j]; a1[j] = r1[j]; }
#pragma unroll
    for (int dx = 0; dx < 5; dx++) {
      float4 v00 = a0[dx], v01 = a0[dx + 1];
      float4 v10 = a1[dx], v11 = a1[dx + 1];
      const float4* wp = &wlds[(dy * 5 + dx) * 7];
#pragma unroll
      for (int k = 0; k < 7; k++) {
        float4 wv = wp[k];
        acc[0][k] += v00.x * wv.x + v00.y * wv.y + v00.z * wv.z + v00.w * wv.w;
        acc[1][k] += v01.x * wv.x + v01.y * wv.y + v01.z * wv.z + v01.w * wv.w;
        acc[2][k] += v10.x * wv.x + v10.y * wv.y + v10.z * wv.z + v10.w * wv.w;
        acc[3][k] += v11.x * wv.x + v11.y * wv.y + v11.z * wv.z + v11.w * wv.w;
      }
    }
  }

#pragma unroll
  for (int k = 0; k < 7; k++) {
    float m = fmaxf(fmaxf(acc[0][k], acc[1][k]), fmaxf(acc[2][k], acc[3][k]));
    h1[(((size_t)b * 7 + k) * 254 + py) * 254 + px] = fmaxf(m, 0.0f);
  }
}

// ---------------- conv2 + relu + maxpool2 + fc1 partials, FUSED ----------------
__global__ __launch_bounds__(256) void conv2fc1_kernel(
    const float* __restrict__ h1,     // [4][7][254][254]
    const float* __restrict__ w,      // [9][7][3][3]
    const float* __restrict__ bias,   // [9]
    const float* __restrict__ fw,     // fc1_w [32][FEAT]
    float* __restrict__ partials) {
  __shared__ float tile[7 * 34 * 35];
  __shared__ float red[4][32];
  int tid = threadIdx.x;
  int b = blockIdx.y;
  int blkx = blockIdx.x;
  int by = blkx >> 3, bx = blkx & 7;
  int y0 = by * 32, x0 = bx * 32;

  for (int i = tid; i < 7 * 34 * 34; i += 256) {
    int c = i / (34 * 34), rem = i % (34 * 34);
    int r = rem / 34, col = rem % 34;
    int gy = y0 + r, gx = x0 + col;
    float v = 0.f;
    if (gy < 254 && gx < 254)
      v = h1[(((size_t)b * 7 + c) * 254 + gy) * 254 + gx];
    tile[(c * 34 + r) * 35 + col] = v;
  }
  __syncthreads();

  int ty = tid >> 4, tx = tid & 15;
  float acc[4][9];
#pragma unroll
  for (int p = 0; p < 4; p++)
#pragma unroll
    for (int k = 0; k < 9; k++) acc[p][k] = bias[k];

  for (int c = 0; c < 7; c++) {
#pragma unroll
    for (int dy = 0; dy < 3; dy++) {
      const float* r0 = &tile[(c * 34 + 2 * ty + dy) * 35 + 2 * tx];
      const float* r1 = r0 + 35;
      float a0[4], a1[4];
#pragma unroll
      for (int j = 0; j < 4; j++) { a0[j] = r0[j]; a1[j] = r1[j]; }
#pragma unroll
      for (int dx = 0; dx < 3; dx++) {
#pragma unroll
        for (int k = 0; k < 9; k++) {
          float wv = w[k * 63 + c * 9 + dy * 3 + dx];
          acc[0][k] += a0[dx] * wv;
          acc[1][k] += a0[dx + 1] * wv;
          acc[2][k] += a1[dx] * wv;
          acc[3][k] += a1[dx + 1] * wv;
        }
      }
    }
  }

  int py = by * 16 + ty, px = bx * 16 + tx;
  bool valid = (py < 126 && px < 126);
  float hv[9];
#pragma unroll
  for (int k = 0; k < 9; k++) {
    float m = fmaxf(fmaxf(acc[0][k], acc[1][k]), fmaxf(acc[2][k], acc[3][k]));
    hv[k] = valid ? fmaxf(m, 0.0f) : 0.0f;
  }
  int fbase = valid ? (py * 126 + px) : 0;

  int lane = tid & 63, wv = tid >> 6;
#pragma unroll 1
  for (int j = 0; j < 32; j++) {
    const float* wj = fw + (size_t)j * FEAT + fbase;
    float s = hv[0] * wj[0];
#pragma unroll
    for (int k = 1; k < 9; k++) s += hv[k] * wj[k * 15876];
#pragma unroll
    for (int off = 32; off > 0; off >>= 1) s += __shfl_down(s, off);
    if (lane == 0) red[wv][j] = s;
  }
  __syncthreads();
  if (tid < 32) {
    float s = red[0][tid] + red[1][tid] + red[2][tid] + red[3][tid];
    partials[((size_t)b * 64 + blkx) * 32 + tid] = s;
  }
}

// ---------------- warp + alpha composite, head MLP fused in-block ----------------
__global__ __launch_bounds__(256) void warp_kernel(
    const float4* __restrict__ x4,
    const float* __restrict__ partials, // [4][64][32]
    const float* __restrict__ b1,       // [32]
    const float* __restrict__ w2,       // [33][32]
    const float* __restrict__ b2,       // [33]
    const float* __restrict__ w3,       // [66][33]
    const float* __restrict__ b3,       // [66]
    float* __restrict__ out) {
  int bid = blockIdx.x;
  int swz = (bid & 7) * 512 + (bid >> 3);   // 4096 blocks, XCD-chunked
  int b = swz >> 10;
  int t = swz & 1023;
  int ty = t >> 5, tx = t & 31;             // 32x32 tiles of 16x16
  int tid = threadIdx.x;

  __shared__ float h32[32], h33[33], th[66];
  if (tid < 32) {
    float s = b1[tid];
    const float* pb = partials + (size_t)b * 64 * 32 + tid;
    for (int blk = 0; blk < 64; blk++) s += pb[blk * 32];
    h32[tid] = fmaxf(s, 0.0f);
  }
  __syncthreads();
  if (tid < 33) {
    float s = b2[tid];
    for (int j = 0; j < 32; j++) s += h32[j] * w2[tid * 32 + j];
    h33[tid] = fmaxf(s, 0.0f);
  }
  __syncthreads();
  if (tid < 66) {
    float s = b3[tid];
    for (int j2 = 0; j2 < 33; j2++) s += h33[j2] * w3[tid * 33 + j2];
    th[tid] = s;
  }
  __syncthreads();

  if (bid == 0) {
    __shared__ float h32b[128], h33b[132], thb[264];
    for (int u = tid; u < 128; u += 256) {
      int bb = u >> 5, j = u & 31;
      float s = b1[j];
      const float* pb = partials + (size_t)bb * 64 * 32 + j;
      for (int blk = 0; blk < 64; blk++) s += pb[blk * 32];
      h32b[u] = fmaxf(s, 0.0f);
    }
    __syncthreads();
    for (int u = tid; u < 132; u += 256) {
      int bb = u / 33, j2 = u % 33;
      float s = b2[j2];
      for (int j = 0; j < 32; j++) s += h32b[bb * 32 + j] * w2[j2 * 32 + j];
      h33b[u] = fmaxf(s, 0.0f);
    }
    __syncthreads();
    for (int u = tid; u < 264; u += 256) {
      int bb = u / 66, v = u % 66;
      float s = b3[v];
      for (int j2 = 0; j2 < 33; j2++) s += h33b[bb * 33 + j2] * w3[v * 33 + j2];
      thb[u] = s;
    }
    __syncthreads();
    float* out_tail = out + 4194304;
    for (int u = tid; u < 176; u += 256) {
      int bb = u / 44, r = u % 44, p = r / 4, ik = r % 4;
      int i = ik >> 1, k = ik & 1;
      const float* T = &thb[bb * 66 + p * 6];
      out_tail[u] = T[i * 3 + 0] * T[k * 3 + 0] + T[i * 3 + 1] * T[k * 3 + 1];
    }
    for (int u = tid; u < 88; u += 256) {
      int bb = u / 22, r = u % 22, p = r / 2, i = r % 2;
      out_tail[176 + u] = thb[bb * 66 + p * 6 + i * 3 + 2];
    }
  }

  int wvi = tid >> 6, l = tid & 63;
  int y = ty * 16 + wvi * 4 + (l >> 4);
  int x = tx * 16 + (l & 15);
  const float4* img0 = x4 + (size_t)b * 6144 * 512 + 262144;
  float fx = (float)x, fy = (float)y;
  const float cn = (1.0f / 512.0f) - 1.0f;

  float4 v00, v01, v10, v11;
  float wx, wy;
  {
    float T0 = th[0], T1 = th[1], T2 = th[2];
    float T3 = th[3], T4 = th[4], T5 = th[5];
    float Cx = 256.0f * ((T0 + T1) * cn + T2) + 255.5f;
    float Cy = 256.0f * ((T3 + T4) * cn + T5) + 255.5f;
    float ix = fmaf(T0, fx, fmaf(T1, fy, Cx));
    float iy = fmaf(T3, fx, fmaf(T4, fy, Cy));
    float xf = floorf(ix), yf = floorf(iy);
    wx = ix - xf; wy = iy - yf;
    int x0i = min(max((int)xf, 0), 511);
    int x1i = min(max((int)xf + 1, 0), 511);
    int y0i = min(max((int)yf, 0), 511);
    int y1i = min(max((int)yf + 1, 0), 511);
    int off00 = y0i * 512 + x0i;
    int dxs = x1i - x0i, dys = (y1i - y0i) * 512;
    v00 = img0[off00];
    v01 = img0[off00 + dxs];
    v10 = img0[off00 + dys];
    v11 = img0[off00 + dys + dxs];
  }

  float4 stack = make_float4(0.f, 0.f, 0.f, 0.f);
#pragma unroll 1
  for (int i = 0; i < NPARTS; i++) {
    float cwx = wx, cwy = wy;
    float4 c00 = v00, c01 = v01, c10 = v10, c11 = v11;
    if (i + 1 < NPARTS) {
      float T0 = th[(i + 1) * 6 + 0], T1 = th[(i + 1) * 6 + 1], T2 = th[(i + 1) * 6 + 2];
      float T3 = th[(i + 1) * 6 + 3], T4 = th[(i + 1) * 6 + 4], T5 = th[(i + 1) * 6 + 5];
      float Cx = 256.0f * ((T0 + T1) * cn + T2) + 255.5f;
      float Cy = 256.0f * ((T3 + T4) * cn + T5) + 255.5f;
      float ix = fmaf(T0, fx, fmaf(T1, fy, Cx));
      float iy = fmaf(T3, fx, fmaf(T4, fy, Cy));
      float xf = floorf(ix), yf = floorf(iy);
      wx = ix - xf; wy = iy - yf;
      int x0i = min(max((int)xf, 0), 511);
      int x1i = min(max((int)xf + 1, 0), 511);
      int y0i = min(max((int)yf, 0), 511);
      int y1i = min(max((int)yf + 1, 0), 511);
      int off00 = y0i * 512 + x0i;
      int dxs = x1i - x0i, dys = (y1i - y0i) * 512;
      const float4* img = img0 + (size_t)(i + 1) * 262144;
      v00 = img[off00];
      v01 = img[off00 + dxs];
      v10 = img[off00 + dys];
      v11 = img[off00 + dys + dxs];
    }
    float w00 = (1.f - cwx) * (1.f - cwy), w01 = cwx * (1.f - cwy);
    float w10 = (1.f - cwx) * cwy, w11 = cwx * cwy;
    float4 val;
    val.x = c00.x * w00 + c01.x * w01 + c10.x * w10 + c11.x * w11;
    val.y = c00.y * w00 + c01.y * w01 + c10.y * w10 + c11.y * w11;
    val.z = c00.z * w00 + c01.z * w01 + c10.z * w10 + c11.z * w11;
    val.w = c00.w * w00 + c01.w * w01 + c10.w * w10 + c11.w * w11;
    if (i == 0) {
      stack = val;
    } else {
      float a = fminf(fmaxf(val.w, 0.0f), 1.0f);
      stack.x = fminf(fmaxf(stack.x - 2.f * a, -1.f), 1.f);
      stack.y = fminf(fmaxf(stack.y - 2.f * a, -1.f), 1.f);
      stack.z = fminf(fmaxf(stack.z - 2.f * a, -1.f), 1.f);
      stack.w = fminf(fmaxf(stack.w - 2.f * a, -1.f), 1.f);
      stack.x = fminf(fmaxf(stack.x + val.x + 1.f, -1.f), 1.f);
      stack.y = fminf(fmaxf(stack.y + val.y + 1.f, -1.f), 1.f);
      stack.z = fminf(fmaxf(stack.z + val.z + 1.f, -1.f), 1.f);
      stack.w = fminf(fmaxf(stack.w + val.w + 1.f, -1.f), 1.f);
    }
  }
  size_t obase = (size_t)b * 4 * 262144 + (size_t)y * 512 + x;
  out[obase] = stack.x;
  out[obase + 262144] = stack.y;
  out[obase + 2 * 262144] = stack.z;
  out[obase + 3 * 262144] = stack.w;
}

extern "C" void kernel_launch(void* const* d_in, const int* in_sizes, int n_in,
                              void* d_out, int out_size, void* d_ws, size_t ws_size,
                              hipStream_t stream) {
  const float4* x4 = (const float4*)d_in[0];
  const float* conv1_w = (const float*)d_in[1];
  const float* conv1_b = (const float*)d_in[2];
  const float* conv2_w = (const float*)d_in[3];
  const float* conv2_b = (const float*)d_in[4];
  const float* fc1_w = (const float*)d_in[5];
  const float* fc1_b = (const float*)d_in[6];
  const float* fc2_w = (const float*)d_in[7];
  const float* fc2_b = (const float*)d_in[8];
  const float* fc3_w = (const float*)d_in[9];
  const float* fc3_b = (const float*)d_in[10];
  float* ws = (float*)d_ws;
  float* out = (float*)d_out;

  // Instrumentation: z=4 -> conv1 work x4 in ONE dispatch (identical writes).
  conv1_kernel<<<dim3(256, 4, 4), 256, 0, stream>>>(x4, conv1_w, conv1_b, ws + OFF_H1);
  conv2fc1_kernel<<<dim3(64, 4), 256, 0, stream>>>(ws + OFF_H1, conv2_w, conv2_b,
                                                   fc1_w, ws + OFF_PART);
  warp_kernel<<<4096, 256, 0, stream>>>(x4, ws + OFF_PART, fc1_b, fc2_w, fc2_b,
                                        fc3_w, fc3_b, out);
}

// Round 18
// 124.267 us; speedup vs baseline: 2.0361x; 2.0361x over previous
//
#include <hip/hip_runtime.h>

#define SS 512
#define NPARTS 11
#define NB 4
#define FEAT (9*126*126)   // 142884

// ws layout (floats)
#define H1SZ (4*7*254*254)       // 1806448
#define OFF_H1 0
#define OFF_PART (OFF_H1 + H1SZ)      // partials [4][64][32] = 8192

// ---------------- conv1 (5x5, 4->7) + relu + maxpool2 ----------------
// 128-thread blocks (8x16 pooled tile, 1 output/thread) -> 2048 blocks, ~6
// resident blocks/CU. Inner loop = pure 4-deep fmaf chains (16 VALU/quad, was 20).
__global__ __launch_bounds__(128) void conv1_kernel(
    const float4* __restrict__ x4,
    const float* __restrict__ w,      // [7][4][5][5]
    const float* __restrict__ bias,   // [7]
    float* __restrict__ h1) {
  __shared__ float4 wlds[175];        // [tap 25][k 7], float4 over c
  int tid = threadIdx.x;
  {
    float* wf = (float*)wlds;
    for (int i = tid; i < 700; i += 128) {
      int tap = i / 28, r = i % 28;
      int k = r >> 2, c = r & 3;
      int dy = tap / 5, dx = tap % 5;
      wf[i] = w[((k * 4 + c) * 5 + dy) * 5 + dx];
    }
  }
  __syncthreads();

  int b = blockIdx.y;
  int by = blockIdx.x >> 4, bx = blockIdx.x & 15;   // 32 x 16 tiles
  int ty = tid >> 4, tx = tid & 15;                 // 8 x 16
  int py = by * 8 + ty, px = bx * 16 + tx;
  if (py >= 254 || px >= 254) return;

  const float4* img = x4 + (size_t)b * 6144 * 512 + (size_t)(2 * py) * 512 + 2 * px;

  float acc[4][7];
#pragma unroll
  for (int p = 0; p < 4; p++)
#pragma unroll
    for (int k = 0; k < 7; k++) acc[p][k] = bias[k];

#pragma unroll 1
  for (int dy = 0; dy < 5; dy++) {
    const float4* r0 = img + dy * 512;
    const float4* r1 = r0 + 512;
    float4 a0[6], a1[6];
#pragma unroll
    for (int j = 0; j < 6; j++) { a0[j] = r0[j]; a1[j] = r1[j]; }
#pragma unroll
    for (int dx = 0; dx < 5; dx++) {
      float4 v00 = a0[dx], v01 = a0[dx + 1];
      float4 v10 = a1[dx], v11 = a1[dx + 1];
      const float4* wp = &wlds[(dy * 5 + dx) * 7];
#pragma unroll
      for (int k = 0; k < 7; k++) {
        float4 wv = wp[k];
        acc[0][k] = fmaf(v00.w, wv.w, fmaf(v00.z, wv.z, fmaf(v00.y, wv.y, fmaf(v00.x, wv.x, acc[0][k]))));
        acc[1][k] = fmaf(v01.w, wv.w, fmaf(v01.z, wv.z, fmaf(v01.y, wv.y, fmaf(v01.x, wv.x, acc[1][k]))));
        acc[2][k] = fmaf(v10.w, wv.w, fmaf(v10.z, wv.z, fmaf(v10.y, wv.y, fmaf(v10.x, wv.x, acc[2][k]))));
        acc[3][k] = fmaf(v11.w, wv.w, fmaf(v11.z, wv.z, fmaf(v11.y, wv.y, fmaf(v11.x, wv.x, acc[3][k]))));
      }
    }
  }

#pragma unroll
  for (int k = 0; k < 7; k++) {
    float m = fmaxf(fmaxf(acc[0][k], acc[1][k]), fmaxf(acc[2][k], acc[3][k]));
    h1[(((size_t)b * 7 + k) * 254 + py) * 254 + px] = fmaxf(m, 0.0f);
  }
}

// ---------------- conv2 + relu + maxpool2 + fc1 partials, FUSED ----------------
__global__ __launch_bounds__(256) void conv2fc1_kernel(
    const float* __restrict__ h1,     // [4][7][254][254]
    const float* __restrict__ w,      // [9][7][3][3]
    const float* __restrict__ bias,   // [9]
    const float* __restrict__ fw,     // fc1_w [32][FEAT]
    float* __restrict__ partials) {
  __shared__ float tile[7 * 34 * 35];
  __shared__ float red[4][32];
  int tid = threadIdx.x;
  int b = blockIdx.y;
  int blkx = blockIdx.x;
  int by = blkx >> 3, bx = blkx & 7;
  int y0 = by * 32, x0 = bx * 32;

  for (int i = tid; i < 7 * 34 * 34; i += 256) {
    int c = i / (34 * 34), rem = i % (34 * 34);
    int r = rem / 34, col = rem % 34;
    int gy = y0 + r, gx = x0 + col;
    float v = 0.f;
    if (gy < 254 && gx < 254)
      v = h1[(((size_t)b * 7 + c) * 254 + gy) * 254 + gx];
    tile[(c * 34 + r) * 35 + col] = v;
  }
  __syncthreads();

  int ty = tid >> 4, tx = tid & 15;
  float acc[4][9];
#pragma unroll
  for (int p = 0; p < 4; p++)
#pragma unroll
    for (int k = 0; k < 9; k++) acc[p][k] = bias[k];

  for (int c = 0; c < 7; c++) {
#pragma unroll
    for (int dy = 0; dy < 3; dy++) {
      const float* r0 = &tile[(c * 34 + 2 * ty + dy) * 35 + 2 * tx];
      const float* r1 = r0 + 35;
      float a0[4], a1[4];
#pragma unroll
      for (int j = 0; j < 4; j++) { a0[j] = r0[j]; a1[j] = r1[j]; }
#pragma unroll
      for (int dx = 0; dx < 3; dx++) {
#pragma unroll
        for (int k = 0; k < 9; k++) {
          float wv = w[k * 63 + c * 9 + dy * 3 + dx];
          acc[0][k] += a0[dx] * wv;
          acc[1][k] += a0[dx + 1] * wv;
          acc[2][k] += a1[dx] * wv;
          acc[3][k] += a1[dx + 1] * wv;
        }
      }
    }
  }

  int py = by * 16 + ty, px = bx * 16 + tx;
  bool valid = (py < 126 && px < 126);
  float hv[9];
#pragma unroll
  for (int k = 0; k < 9; k++) {
    float m = fmaxf(fmaxf(acc[0][k], acc[1][k]), fmaxf(acc[2][k], acc[3][k]));
    hv[k] = valid ? fmaxf(m, 0.0f) : 0.0f;
  }
  int fbase = valid ? (py * 126 + px) : 0;

  int lane = tid & 63, wv = tid >> 6;
#pragma unroll 1
  for (int j = 0; j < 32; j++) {
    const float* wj = fw + (size_t)j * FEAT + fbase;
    float s = hv[0] * wj[0];
#pragma unroll
    for (int k = 1; k < 9; k++) s += hv[k] * wj[k * 15876];
#pragma unroll
    for (int off = 32; off > 0; off >>= 1) s += __shfl_down(s, off);
    if (lane == 0) red[wv][j] = s;
  }
  __syncthreads();
  if (tid < 32) {
    float s = red[0][tid] + red[1][tid] + red[2][tid] + red[3][tid];
    partials[((size_t)b * 64 + blkx) * 32 + tid] = s;
  }
}

// ---------------- warp + alpha composite, head MLP fused in-block ----------------
__global__ __launch_bounds__(256) void warp_kernel(
    const float4* __restrict__ x4,
    const float* __restrict__ partials, // [4][64][32]
    const float* __restrict__ b1,       // [32]
    const float* __restrict__ w2,       // [33][32]
    const float* __restrict__ b2,       // [33]
    const float* __restrict__ w3,       // [66][33]
    const float* __restrict__ b3,       // [66]
    float* __restrict__ out) {
  int bid = blockIdx.x;
  int swz = (bid & 7) * 512 + (bid >> 3);   // 4096 blocks, XCD-chunked
  int b = swz >> 10;
  int t = swz & 1023;
  int ty = t >> 5, tx = t & 31;             // 32x32 tiles of 16x16
  int tid = threadIdx.x;

  __shared__ float h32[32], h33[33], th[66];
  if (tid < 32) {
    float s = b1[tid];
    const float* pb = partials + (size_t)b * 64 * 32 + tid;
    for (int blk = 0; blk < 64; blk++) s += pb[blk * 32];
    h32[tid] = fmaxf(s, 0.0f);
  }
  __syncthreads();
  if (tid < 33) {
    float s = b2[tid];
    for (int j = 0; j < 32; j++) s += h32[j] * w2[tid * 32 + j];
    h33[tid] = fmaxf(s, 0.0f);
  }
  __syncthreads();
  if (tid < 66) {
    float s = b3[tid];
    for (int j2 = 0; j2 < 33; j2++) s += h33[j2] * w3[tid * 33 + j2];
    th[tid] = s;
  }
  __syncthreads();

  if (bid == 0) {
    __shared__ float h32b[128], h33b[132], thb[264];
    for (int u = tid; u < 128; u += 256) {
      int bb = u >> 5, j = u & 31;
      float s = b1[j];
      const float* pb = partials + (size_t)bb * 64 * 32 + j;
      for (int blk = 0; blk < 64; blk++) s += pb[blk * 32];
      h32b[u] = fmaxf(s, 0.0f);
    }
    __syncthreads();
    for (int u = tid; u < 132; u += 256) {
      int bb = u / 33, j2 = u % 33;
      float s = b2[j2];
      for (int j = 0; j < 32; j++) s += h32b[bb * 32 + j] * w2[j2 * 32 + j];
      h33b[u] = fmaxf(s, 0.0f);
    }
    __syncthreads();
    for (int u = tid; u < 264; u += 256) {
      int bb = u / 66, v = u % 66;
      float s = b3[v];
      for (int j2 = 0; j2 < 33; j2++) s += h33b[bb * 33 + j2] * w3[v * 33 + j2];
      thb[u] = s;
    }
    __syncthreads();
    float* out_tail = out + 4194304;
    for (int u = tid; u < 176; u += 256) {
      int bb = u / 44, r = u % 44, p = r / 4, ik = r % 4;
      int i = ik >> 1, k = ik & 1;
      const float* T = &thb[bb * 66 + p * 6];
      out_tail[u] = T[i * 3 + 0] * T[k * 3 + 0] + T[i * 3 + 1] * T[k * 3 + 1];
    }
    for (int u = tid; u < 88; u += 256) {
      int bb = u / 22, r = u % 22, p = r / 2, i = r % 2;
      out_tail[176 + u] = thb[bb * 66 + p * 6 + i * 3 + 2];
    }
  }

  int wvi = tid >> 6, l = tid & 63;
  int y = ty * 16 + wvi * 4 + (l >> 4);
  int x = tx * 16 + (l & 15);
  const float4* img0 = x4 + (size_t)b * 6144 * 512 + 262144;
  float fx = (float)x, fy = (float)y;
  const float cn = (1.0f / 512.0f) - 1.0f;

  float4 v00, v01, v10, v11;
  float wx, wy;
  {
    float T0 = th[0], T1 = th[1], T2 = th[2];
    float T3 = th[3], T4 = th[4], T5 = th[5];
    float Cx = 256.0f * ((T0 + T1) * cn + T2) + 255.5f;
    float Cy = 256.0f * ((T3 + T4) * cn + T5) + 255.5f;
    float ix = fmaf(T0, fx, fmaf(T1, fy, Cx));
    float iy = fmaf(T3, fx, fmaf(T4, fy, Cy));
    float xf = floorf(ix), yf = floorf(iy);
    wx = ix - xf; wy = iy - yf;
    int x0i = min(max((int)xf, 0), 511);
    int x1i = min(max((int)xf + 1, 0), 511);
    int y0i = min(max((int)yf, 0), 511);
    int y1i = min(max((int)yf + 1, 0), 511);
    int off00 = y0i * 512 + x0i;
    int dxs = x1i - x0i, dys = (y1i - y0i) * 512;
    v00 = img0[off00];
    v01 = img0[off00 + dxs];
    v10 = img0[off00 + dys];
    v11 = img0[off00 + dys + dxs];
  }

  float4 stack = make_float4(0.f, 0.f, 0.f, 0.f);
#pragma unroll 1
  for (int i = 0; i < NPARTS; i++) {
    float cwx = wx, cwy = wy;
    float4 c00 = v00, c01 = v01, c10 = v10, c11 = v11;
    if (i + 1 < NPARTS) {
      float T0 = th[(i + 1) * 6 + 0], T1 = th[(i + 1) * 6 + 1], T2 = th[(i + 1) * 6 + 2];
      float T3 = th[(i + 1) * 6 + 3], T4 = th[(i + 1) * 6 + 4], T5 = th[(i + 1) * 6 + 5];
      float Cx = 256.0f * ((T0 + T1) * cn + T2) + 255.5f;
      float Cy = 256.0f * ((T3 + T4) * cn + T5) + 255.5f;
      float ix = fmaf(T0, fx, fmaf(T1, fy, Cx));
      float iy = fmaf(T3, fx, fmaf(T4, fy, Cy));
      float xf = floorf(ix), yf = floorf(iy);
      wx = ix - xf; wy = iy - yf;
      int x0i = min(max((int)xf, 0), 511);
      int x1i = min(max((int)xf + 1, 0), 511);
      int y0i = min(max((int)yf, 0), 511);
      int y1i = min(max((int)yf + 1, 0), 511);
      int off00 = y0i * 512 + x0i;
      int dxs = x1i - x0i, dys = (y1i - y0i) * 512;
      const float4* img = img0 + (size_t)(i + 1) * 262144;
      v00 = img[off00];
      v01 = img[off00 + dxs];
      v10 = img[off00 + dys];
      v11 = img[off00 + dys + dxs];
    }
    float w00 = (1.f - cwx) * (1.f - cwy), w01 = cwx * (1.f - cwy);
    float w10 = (1.f - cwx) * cwy, w11 = cwx * cwy;
    float4 val;
    val.x = c00.x * w00 + c01.x * w01 + c10.x * w10 + c11.x * w11;
    val.y = c00.y * w00 + c01.y * w01 + c10.y * w10 + c11.y * w11;
    val.z = c00.z * w00 + c01.z * w01 + c10.z * w10 + c11.z * w11;
    val.w = c00.w * w00 + c01.w * w01 + c10.w * w10 + c11.w * w11;
    if (i == 0) {
      stack = val;
    } else {
      float a = fminf(fmaxf(val.w, 0.0f), 1.0f);
      stack.x = fminf(fmaxf(stack.x - 2.f * a, -1.f), 1.f);
      stack.y = fminf(fmaxf(stack.y - 2.f * a, -1.f), 1.f);
      stack.z = fminf(fmaxf(stack.z - 2.f * a, -1.f), 1.f);
      stack.w = fminf(fmaxf(stack.w - 2.f * a, -1.f), 1.f);
      stack.x = fminf(fmaxf(stack.x + val.x + 1.f, -1.f), 1.f);
      stack.y = fminf(fmaxf(stack.y + val.y + 1.f, -1.f), 1.f);
      stack.z = fminf(fmaxf(stack.z + val.z + 1.f, -1.f), 1.f);
      stack.w = fminf(fmaxf(stack.w + val.w + 1.f, -1.f), 1.f);
    }
  }
  size_t obase = (size_t)b * 4 * 262144 + (size_t)y * 512 + x;
  out[obase] = stack.x;
  out[obase + 262144] = stack.y;
  out[obase + 2 * 262144] = stack.z;
  out[obase + 3 * 262144] = stack.w;
}

extern "C" void kernel_launch(void* const* d_in, const int* in_sizes, int n_in,
                              void* d_out, int out_size, void* d_ws, size_t ws_size,
                              hipStream_t stream) {
  const float4* x4 = (const float4*)d_in[0];
  const float* conv1_w = (const float*)d_in[1];
  const float* conv1_b = (const float*)d_in[2];
  const float* conv2_w = (const float*)d_in[3];
  const float* conv2_b = (const float*)d_in[4];
  const float* fc1_w = (const float*)d_in[5];
  const float* fc1_b = (const float*)d_in[6];
  const float* fc2_w = (const float*)d_in[7];
  const float* fc2_b = (const float*)d_in[8];
  const float* fc3_w = (const float*)d_in[9];
  const float* fc3_b = (const float*)d_in[10];
  float* ws = (float*)d_ws;
  float* out = (float*)d_out;

  conv1_kernel<<<dim3(512, 4), 128, 0, stream>>>(x4, conv1_w, conv1_b, ws + OFF_H1);
  conv2fc1_kernel<<<dim3(64, 4), 256, 0, stream>>>(ws + OFF_H1, conv2_w, conv2_b,
                                                   fc1_w, ws + OFF_PART);
  warp_kernel<<<4096, 256, 0, stream>>>(x4, ws + OFF_PART, fc1_b, fc2_w, fc2_b,
                                        fc3_w, fc3_b, out);
}

// Round 21
// 113.707 us; speedup vs baseline: 2.2252x; 1.0929x over previous
//
#include <hip/hip_runtime.h>

#define SS 512
#define NPARTS 11
#define NB 4
#define FEAT (9*126*126)   // 142884

// ws layout (floats)
#define H1SZ (4*7*254*254)       // 1806448
#define OFF_H1 0
#define OFF_PART (OFF_H1 + H1SZ)      // partials [4][64][32] = 8192

typedef float f2 __attribute__((ext_vector_type(2)));

// ---------------- conv1 (5x5, 4->7) + relu + maxpool2, packed fp32 ----------------
// v_pk_fma_f32 via llvm.fma.v2f32: 2 fp32 MAC/inst, full precision.
// 128-thread blocks (8x16 pooled tile); per-thread MAC stream 1400 (was 2800).
__global__ __launch_bounds__(128) void conv1_kernel(
    const float4* __restrict__ x4,
    const float* __restrict__ w,      // [7][4][5][5]
    const float* __restrict__ bias,   // [7]
    float* __restrict__ h1) {
  __shared__ f2 wl[350];              // [tap 25][k 7][2]: {c0,c1},{c2,c3}
  int tid = threadIdx.x;
  for (int i = tid; i < 175; i += 128) {
    int tap = i / 7, k = i % 7;
    int dy = tap / 5, dx = tap % 5;
    f2 lo, hi;
    lo.x = w[((k * 4 + 0) * 5 + dy) * 5 + dx];
    lo.y = w[((k * 4 + 1) * 5 + dy) * 5 + dx];
    hi.x = w[((k * 4 + 2) * 5 + dy) * 5 + dx];
    hi.y = w[((k * 4 + 3) * 5 + dy) * 5 + dx];
    wl[2 * i] = lo;
    wl[2 * i + 1] = hi;
  }
  __syncthreads();

  int b = blockIdx.y;
  int by = blockIdx.x >> 4, bx = blockIdx.x & 15;   // 32 x 16 tiles
  int ty = tid >> 4, tx = tid & 15;                 // 8 x 16
  int py = by * 8 + ty, px = bx * 16 + tx;
  if (py >= 254 || px >= 254) return;

  const float4* img = x4 + (size_t)b * 6144 * 512 + (size_t)(2 * py) * 512 + 2 * px;

  f2 acc[4][7];
#pragma unroll
  for (int p = 0; p < 4; p++)
#pragma unroll
    for (int k = 0; k < 7; k++) { acc[p][k].x = bias[k]; acc[p][k].y = 0.0f; }

#pragma unroll 1
  for (int dy = 0; dy < 5; dy++) {
    const float4* r0 = img + dy * 512;
    const float4* r1 = r0 + 512;
    float4 a0[6], a1[6];
#pragma unroll
    for (int j = 0; j < 6; j++) { a0[j] = r0[j]; a1[j] = r1[j]; }
#pragma unroll
    for (int dx = 0; dx < 5; dx++) {
      f2 v00l; v00l.x = a0[dx].x;     v00l.y = a0[dx].y;
      f2 v00h; v00h.x = a0[dx].z;     v00h.y = a0[dx].w;
      f2 v01l; v01l.x = a0[dx + 1].x; v01l.y = a0[dx + 1].y;
      f2 v01h; v01h.x = a0[dx + 1].z; v01h.y = a0[dx + 1].w;
      f2 v10l; v10l.x = a1[dx].x;     v10l.y = a1[dx].y;
      f2 v10h; v10h.x = a1[dx].z;     v10h.y = a1[dx].w;
      f2 v11l; v11l.x = a1[dx + 1].x; v11l.y = a1[dx + 1].y;
      f2 v11h; v11h.x = a1[dx + 1].z; v11h.y = a1[dx + 1].w;
      const f2* wp = &wl[(dy * 5 + dx) * 14];
#pragma unroll
      for (int k = 0; k < 7; k++) {
        f2 wlo = wp[2 * k], whi = wp[2 * k + 1];
        acc[0][k] = __builtin_elementwise_fma(v00h, whi,
                    __builtin_elementwise_fma(v00l, wlo, acc[0][k]));
        acc[1][k] = __builtin_elementwise_fma(v01h, whi,
                    __builtin_elementwise_fma(v01l, wlo, acc[1][k]));
        acc[2][k] = __builtin_elementwise_fma(v10h, whi,
                    __builtin_elementwise_fma(v10l, wlo, acc[2][k]));
        acc[3][k] = __builtin_elementwise_fma(v11h, whi,
                    __builtin_elementwise_fma(v11l, wlo, acc[3][k]));
      }
    }
  }

#pragma unroll
  for (int k = 0; k < 7; k++) {
    float s0 = acc[0][k].x + acc[0][k].y;
    float s1 = acc[1][k].x + acc[1][k].y;
    float s2 = acc[2][k].x + acc[2][k].y;
    float s3 = acc[3][k].x + acc[3][k].y;
    float m = fmaxf(fmaxf(s0, s1), fmaxf(s2, s3));
    h1[(((size_t)b * 7 + k) * 254 + py) * 254 + px] = fmaxf(m, 0.0f);
  }
}

// ---------------- conv2 + relu + maxpool2 + fc1 partials, FUSED ----------------
__global__ __launch_bounds__(256) void conv2fc1_kernel(
    const float* __restrict__ h1,     // [4][7][254][254]
    const float* __restrict__ w,      // [9][7][3][3]
    const float* __restrict__ bias,   // [9]
    const float* __restrict__ fw,     // fc1_w [32][FEAT]
    float* __restrict__ partials) {
  __shared__ float tile[7 * 34 * 35];
  __shared__ float red[4][32];
  int tid = threadIdx.x;
  int b = blockIdx.y;
  int blkx = blockIdx.x;
  int by = blkx >> 3, bx = blkx & 7;
  int y0 = by * 32, x0 = bx * 32;

  for (int i = tid; i < 7 * 34 * 34; i += 256) {
    int c = i / (34 * 34), rem = i % (34 * 34);
    int r = rem / 34, col = rem % 34;
    int gy = y0 + r, gx = x0 + col;
    float v = 0.f;
    if (gy < 254 && gx < 254)
      v = h1[(((size_t)b * 7 + c) * 254 + gy) * 254 + gx];
    tile[(c * 34 + r) * 35 + col] = v;
  }
  __syncthreads();

  int ty = tid >> 4, tx = tid & 15;
  float acc[4][9];
#pragma unroll
  for (int p = 0; p < 4; p++)
#pragma unroll
    for (int k = 0; k < 9; k++) acc[p][k] = bias[k];

  for (int c = 0; c < 7; c++) {
#pragma unroll
    for (int dy = 0; dy < 3; dy++) {
      const float* r0 = &tile[(c * 34 + 2 * ty + dy) * 35 + 2 * tx];
      const float* r1 = r0 + 35;
      float a0[4], a1[4];
#pragma unroll
      for (int j = 0; j < 4; j++) { a0[j] = r0[j]; a1[j] = r1[j]; }
#pragma unroll
      for (int dx = 0; dx < 3; dx++) {
#pragma unroll
        for (int k = 0; k < 9; k++) {
          float wv = w[k * 63 + c * 9 + dy * 3 + dx];
          acc[0][k] += a0[dx] * wv;
          acc[1][k] += a0[dx + 1] * wv;
          acc[2][k] += a1[dx] * wv;
          acc[3][k] += a1[dx + 1] * wv;
        }
      }
    }
  }

  int py = by * 16 + ty, px = bx * 16 + tx;
  bool valid = (py < 126 && px < 126);
  float hv[9];
#pragma unroll
  for (int k = 0; k < 9; k++) {
    float m = fmaxf(fmaxf(acc[0][k], acc[1][k]), fmaxf(acc[2][k], acc[3][k]));
    hv[k] = valid ? fmaxf(m, 0.0f) : 0.0f;
  }
  int fbase = valid ? (py * 126 + px) : 0;

  int lane = tid & 63, wv = tid >> 6;
#pragma unroll 1
  for (int j = 0; j < 32; j++) {
    const float* wj = fw + (size_t)j * FEAT + fbase;
    float s = hv[0] * wj[0];
#pragma unroll
    for (int k = 1; k < 9; k++) s += hv[k] * wj[k * 15876];
#pragma unroll
    for (int off = 32; off > 0; off >>= 1) s += __shfl_down(s, off);
    if (lane == 0) red[wv][j] = s;
  }
  __syncthreads();
  if (tid < 32) {
    float s = red[0][tid] + red[1][tid] + red[2][tid] + red[3][tid];
    partials[((size_t)b * 64 + blkx) * 32 + tid] = s;
  }
}

// ---------------- warp + alpha composite, head MLP fused in-block ----------------
__global__ __launch_bounds__(256) void warp_kernel(
    const float4* __restrict__ x4,
    const float* __restrict__ partials, // [4][64][32]
    const float* __restrict__ b1,       // [32]
    const float* __restrict__ w2,       // [33][32]
    const float* __restrict__ b2,       // [33]
    const float* __restrict__ w3,       // [66][33]
    const float* __restrict__ b3,       // [66]
    float* __restrict__ out) {
  int bid = blockIdx.x;
  int swz = (bid & 7) * 512 + (bid >> 3);   // 4096 blocks, XCD-chunked
  int b = swz >> 10;
  int t = swz & 1023;
  int ty = t >> 5, tx = t & 31;             // 32x32 tiles of 16x16
  int tid = threadIdx.x;

  __shared__ float h32[32], h33[33], th[66];
  if (tid < 32) {
    float s = b1[tid];
    const float* pb = partials + (size_t)b * 64 * 32 + tid;
    for (int blk = 0; blk < 64; blk++) s += pb[blk * 32];
    h32[tid] = fmaxf(s, 0.0f);
  }
  __syncthreads();
  if (tid < 33) {
    float s = b2[tid];
    for (int j = 0; j < 32; j++) s += h32[j] * w2[tid * 32 + j];
    h33[tid] = fmaxf(s, 0.0f);
  }
  __syncthreads();
  if (tid < 66) {
    float s = b3[tid];
    for (int j2 = 0; j2 < 33; j2++) s += h33[j2] * w3[tid * 33 + j2];
    th[tid] = s;
  }
  __syncthreads();

  if (bid == 0) {
    __shared__ float h32b[128], h33b[132], thb[264];
    for (int u = tid; u < 128; u += 256) {
      int bb = u >> 5, j = u & 31;
      float s = b1[j];
      const float* pb = partials + (size_t)bb * 64 * 32 + j;
      for (int blk = 0; blk < 64; blk++) s += pb[blk * 32];
      h32b[u] = fmaxf(s, 0.0f);
    }
    __syncthreads();
    for (int u = tid; u < 132; u += 256) {
      int bb = u / 33, j2 = u % 33;
      float s = b2[j2];
      for (int j = 0; j < 32; j++) s += h32b[bb * 32 + j] * w2[j2 * 32 + j];
      h33b[u] = fmaxf(s, 0.0f);
    }
    __syncthreads();
    for (int u = tid; u < 264; u += 256) {
      int bb = u / 66, v = u % 66;
      float s = b3[v];
      for (int j2 = 0; j2 < 33; j2++) s += h33b[bb * 33 + j2] * w3[v * 33 + j2];
      thb[u] = s;
    }
    __syncthreads();
    float* out_tail = out + 4194304;
    for (int u = tid; u < 176; u += 256) {
      int bb = u / 44, r = u % 44, p = r / 4, ik = r % 4;
      int i = ik >> 1, k = ik & 1;
      const float* T = &thb[bb * 66 + p * 6];
      out_tail[u] = T[i * 3 + 0] * T[k * 3 + 0] + T[i * 3 + 1] * T[k * 3 + 1];
    }
    for (int u = tid; u < 88; u += 256) {
      int bb = u / 22, r = u % 22, p = r / 2, i = r % 2;
      out_tail[176 + u] = thb[bb * 66 + p * 6 + i * 3 + 2];
    }
  }

  int wvi = tid >> 6, l = tid & 63;
  int y = ty * 16 + wvi * 4 + (l >> 4);
  int x = tx * 16 + (l & 15);
  const float4* img0 = x4 + (size_t)b * 6144 * 512 + 262144;
  float fx = (float)x, fy = (float)y;
  const float cn = (1.0f / 512.0f) - 1.0f;

  float4 v00, v01, v10, v11;
  float wx, wy;
  {
    float T0 = th[0], T1 = th[1], T2 = th[2];
    float T3 = th[3], T4 = th[4], T5 = th[5];
    float Cx = 256.0f * ((T0 + T1) * cn + T2) + 255.5f;
    float Cy = 256.0f * ((T3 + T4) * cn + T5) + 255.5f;
    float ix = fmaf(T0, fx, fmaf(T1, fy, Cx));
    float iy = fmaf(T3, fx, fmaf(T4, fy, Cy));
    float xf = floorf(ix), yf = floorf(iy);
    wx = ix - xf; wy = iy - yf;
    int x0i = min(max((int)xf, 0), 511);
    int x1i = min(max((int)xf + 1, 0), 511);
    int y0i = min(max((int)yf, 0), 511);
    int y1i = min(max((int)yf + 1, 0), 511);
    int off00 = y0i * 512 + x0i;
    int dxs = x1i - x0i, dys = (y1i - y0i) * 512;
    v00 = img0[off00];
    v01 = img0[off00 + dxs];
    v10 = img0[off00 + dys];
    v11 = img0[off00 + dys + dxs];
  }

  float4 stack = make_float4(0.f, 0.f, 0.f, 0.f);
#pragma unroll 1
  for (int i = 0; i < NPARTS; i++) {
    float cwx = wx, cwy = wy;
    float4 c00 = v00, c01 = v01, c10 = v10, c11 = v11;
    if (i + 1 < NPARTS) {
      float T0 = th[(i + 1) * 6 + 0], T1 = th[(i + 1) * 6 + 1], T2 = th[(i + 1) * 6 + 2];
      float T3 = th[(i + 1) * 6 + 3], T4 = th[(i + 1) * 6 + 4], T5 = th[(i + 1) * 6 + 5];
      float Cx = 256.0f * ((T0 + T1) * cn + T2) + 255.5f;
      float Cy = 256.0f * ((T3 + T4) * cn + T5) + 255.5f;
      float ix = fmaf(T0, fx, fmaf(T1, fy, Cx));
      float iy = fmaf(T3, fx, fmaf(T4, fy, Cy));
      float xf = floorf(ix), yf = floorf(iy);
      wx = ix - xf; wy = iy - yf;
      int x0i = min(max((int)xf, 0), 511);
      int x1i = min(max((int)xf + 1, 0), 511);
      int y0i = min(max((int)yf, 0), 511);
      int y1i = min(max((int)yf + 1, 0), 511);
      int off00 = y0i * 512 + x0i;
      int dxs = x1i - x0i, dys = (y1i - y0i) * 512;
      const float4* img = img0 + (size_t)(i + 1) * 262144;
      v00 = img[off00];
      v01 = img[off00 + dxs];
      v10 = img[off00 + dys];
      v11 = img[off00 + dys + dxs];
    }
    float w00 = (1.f - cwx) * (1.f - cwy), w01 = cwx * (1.f - cwy);
    float w10 = (1.f - cwx) * cwy, w11 = cwx * cwy;
    float4 val;
    val.x = c00.x * w00 + c01.x * w01 + c10.x * w10 + c11.x * w11;
    val.y = c00.y * w00 + c01.y * w01 + c10.y * w10 + c11.y * w11;
    val.z = c00.z * w00 + c01.z * w01 + c10.z * w10 + c11.z * w11;
    val.w = c00.w * w00 + c01.w * w01 + c10.w * w10 + c11.w * w11;
    if (i == 0) {
      stack = val;
    } else {
      float a = fminf(fmaxf(val.w, 0.0f), 1.0f);
      stack.x = fminf(fmaxf(stack.x - 2.f * a, -1.f), 1.f);
      stack.y = fminf(fmaxf(stack.y - 2.f * a, -1.f), 1.f);
      stack.z = fminf(fmaxf(stack.z - 2.f * a, -1.f), 1.f);
      stack.w = fminf(fmaxf(stack.w - 2.f * a, -1.f), 1.f);
      stack.x = fminf(fmaxf(stack.x + val.x + 1.f, -1.f), 1.f);
      stack.y = fminf(fmaxf(stack.y + val.y + 1.f, -1.f), 1.f);
      stack.z = fminf(fmaxf(stack.z + val.z + 1.f, -1.f), 1.f);
      stack.w = fminf(fmaxf(stack.w + val.w + 1.f, -1.f), 1.f);
    }
  }
  size_t obase = (size_t)b * 4 * 262144 + (size_t)y * 512 + x;
  out[obase] = stack.x;
  out[obase + 262144] = stack.y;
  out[obase + 2 * 262144] = stack.z;
  out[obase + 3 * 262144] = stack.w;
}

extern "C" void kernel_launch(void* const* d_in, const int* in_sizes, int n_in,
                              void* d_out, int out_size, void* d_ws, size_t ws_size,
                              hipStream_t stream) {
  const float4* x4 = (const float4*)d_in[0];
  const float* conv1_w = (const float*)d_in[1];
  const float* conv1_b = (const float*)d_in[2];
  const float* conv2_w = (const float*)d_in[3];
  const float* conv2_b = (const float*)d_in[4];
  const float* fc1_w = (const float*)d_in[5];
  const float* fc1_b = (const float*)d_in[6];
  const float* fc2_w = (const float*)d_in[7];
  const float* fc2_b = (const float*)d_in[8];
  const float* fc3_w = (const float*)d_in[9];
  const float* fc3_b = (const float*)d_in[10];
  float* ws = (float*)d_ws;
  float* out = (float*)d_out;

  conv1_kernel<<<dim3(512, 4), 128, 0, stream>>>(x4, conv1_w, conv1_b, ws + OFF_H1);
  conv2fc1_kernel<<<dim3(64, 4), 256, 0, stream>>>(ws + OFF_H1, conv2_w, conv2_b,
                                                   fc1_w, ws + OFF_PART);
  warp_kernel<<<4096, 256, 0, stream>>>(x4, ws + OFF_PART, fc1_b, fc2_w, fc2_b,
                                        fc3_w, fc3_b, out);
}

// Round 22
// 113.523 us; speedup vs baseline: 2.2288x; 1.0016x over previous
//
#include <hip/hip_runtime.h>

#define SS 512
#define NPARTS 11
#define NB 4
#define FEAT (9*126*126)   // 142884

// ws layout (floats)
#define H1SZ (4*7*254*254)       // 1806448
#define OFF_H1 0
#define OFF_PART (OFF_H1 + H1SZ)      // partials [4][64][32] = 8192

typedef float f2 __attribute__((ext_vector_type(2)));

// ---------------- conv1 (5x5, 4->7) + relu + maxpool2, packed fp32 ----------------
// v_pk_fma_f32; dy loop FULLY unrolled -> row loads CSE'd (36 unique float4,
// was 60) ; weights read as ds_read_b128 (175 reads, was 350 b64).
__global__ __launch_bounds__(128) void conv1_kernel(
    const float4* __restrict__ x4,
    const float* __restrict__ w,      // [7][4][5][5]
    const float* __restrict__ bias,   // [7]
    float* __restrict__ h1) {
  __shared__ float4 wl[175];          // [tap 25][k 7]: {c0,c1,c2,c3}
  int tid = threadIdx.x;
  for (int i = tid; i < 175; i += 128) {
    int tap = i / 7, k = i % 7;
    int dy = tap / 5, dx = tap % 5;
    float4 v;
    v.x = w[((k * 4 + 0) * 5 + dy) * 5 + dx];
    v.y = w[((k * 4 + 1) * 5 + dy) * 5 + dx];
    v.z = w[((k * 4 + 2) * 5 + dy) * 5 + dx];
    v.w = w[((k * 4 + 3) * 5 + dy) * 5 + dx];
    wl[i] = v;
  }
  __syncthreads();

  int b = blockIdx.y;
  int by = blockIdx.x >> 4, bx = blockIdx.x & 15;   // 32 x 16 tiles
  int ty = tid >> 4, tx = tid & 15;                 // 8 x 16
  int py = by * 8 + ty, px = bx * 16 + tx;
  if (py >= 254 || px >= 254) return;

  const float4* img = x4 + (size_t)b * 6144 * 512 + (size_t)(2 * py) * 512 + 2 * px;

  f2 acc[4][7];
#pragma unroll
  for (int p = 0; p < 4; p++)
#pragma unroll
    for (int k = 0; k < 7; k++) { acc[p][k].x = bias[k]; acc[p][k].y = 0.0f; }

#pragma unroll
  for (int dy = 0; dy < 5; dy++) {
    const float4* r0 = img + dy * 512;
    const float4* r1 = r0 + 512;
    float4 a0[6], a1[6];
#pragma unroll
    for (int j = 0; j < 6; j++) { a0[j] = r0[j]; a1[j] = r1[j]; }   // CSE across dy
#pragma unroll
    for (int dx = 0; dx < 5; dx++) {
      f2 v00l; v00l.x = a0[dx].x;     v00l.y = a0[dx].y;
      f2 v00h; v00h.x = a0[dx].z;     v00h.y = a0[dx].w;
      f2 v01l; v01l.x = a0[dx + 1].x; v01l.y = a0[dx + 1].y;
      f2 v01h; v01h.x = a0[dx + 1].z; v01h.y = a0[dx + 1].w;
      f2 v10l; v10l.x = a1[dx].x;     v10l.y = a1[dx].y;
      f2 v10h; v10h.x = a1[dx].z;     v10h.y = a1[dx].w;
      f2 v11l; v11l.x = a1[dx + 1].x; v11l.y = a1[dx + 1].y;
      f2 v11h; v11h.x = a1[dx + 1].z; v11h.y = a1[dx + 1].w;
      const float4* wp = &wl[(dy * 5 + dx) * 7];
#pragma unroll
      for (int k = 0; k < 7; k++) {
        float4 wv4 = wp[k];                 // one ds_read_b128
        f2 wlo; wlo.x = wv4.x; wlo.y = wv4.y;
        f2 whi; whi.x = wv4.z; whi.y = wv4.w;
        acc[0][k] = __builtin_elementwise_fma(v00h, whi,
                    __builtin_elementwise_fma(v00l, wlo, acc[0][k]));
        acc[1][k] = __builtin_elementwise_fma(v01h, whi,
                    __builtin_elementwise_fma(v01l, wlo, acc[1][k]));
        acc[2][k] = __builtin_elementwise_fma(v10h, whi,
                    __builtin_elementwise_fma(v10l, wlo, acc[2][k]));
        acc[3][k] = __builtin_elementwise_fma(v11h, whi,
                    __builtin_elementwise_fma(v11l, wlo, acc[3][k]));
      }
    }
  }

#pragma unroll
  for (int k = 0; k < 7; k++) {
    float s0 = acc[0][k].x + acc[0][k].y;
    float s1 = acc[1][k].x + acc[1][k].y;
    float s2 = acc[2][k].x + acc[2][k].y;
    float s3 = acc[3][k].x + acc[3][k].y;
    float m = fmaxf(fmaxf(s0, s1), fmaxf(s2, s3));
    h1[(((size_t)b * 7 + k) * 254 + py) * 254 + px] = fmaxf(m, 0.0f);
  }
}

// ---------------- conv2 + relu + maxpool2 + fc1 partials, FUSED ----------------
__global__ __launch_bounds__(256) void conv2fc1_kernel(
    const float* __restrict__ h1,     // [4][7][254][254]
    const float* __restrict__ w,      // [9][7][3][3]
    const float* __restrict__ bias,   // [9]
    const float* __restrict__ fw,     // fc1_w [32][FEAT]
    float* __restrict__ partials) {
  __shared__ float tile[7 * 34 * 35];
  __shared__ float red[4][32];
  int tid = threadIdx.x;
  int b = blockIdx.y;
  int blkx = blockIdx.x;
  int by = blkx >> 3, bx = blkx & 7;
  int y0 = by * 32, x0 = bx * 32;

  for (int i = tid; i < 7 * 34 * 34; i += 256) {
    int c = i / (34 * 34), rem = i % (34 * 34);
    int r = rem / 34, col = rem % 34;
    int gy = y0 + r, gx = x0 + col;
    float v = 0.f;
    if (gy < 254 && gx < 254)
      v = h1[(((size_t)b * 7 + c) * 254 + gy) * 254 + gx];
    tile[(c * 34 + r) * 35 + col] = v;
  }
  __syncthreads();

  int ty = tid >> 4, tx = tid & 15;
  float acc[4][9];
#pragma unroll
  for (int p = 0; p < 4; p++)
#pragma unroll
    for (int k = 0; k < 9; k++) acc[p][k] = bias[k];

  for (int c = 0; c < 7; c++) {
#pragma unroll
    for (int dy = 0; dy < 3; dy++) {
      const float* r0 = &tile[(c * 34 + 2 * ty + dy) * 35 + 2 * tx];
      const float* r1 = r0 + 35;
      float a0[4], a1[4];
#pragma unroll
      for (int j = 0; j < 4; j++) { a0[j] = r0[j]; a1[j] = r1[j]; }
#pragma unroll
      for (int dx = 0; dx < 3; dx++) {
#pragma unroll
        for (int k = 0; k < 9; k++) {
          float wv = w[k * 63 + c * 9 + dy * 3 + dx];
          acc[0][k] += a0[dx] * wv;
          acc[1][k] += a0[dx + 1] * wv;
          acc[2][k] += a1[dx] * wv;
          acc[3][k] += a1[dx + 1] * wv;
        }
      }
    }
  }

  int py = by * 16 + ty, px = bx * 16 + tx;
  bool valid = (py < 126 && px < 126);
  float hv[9];
#pragma unroll
  for (int k = 0; k < 9; k++) {
    float m = fmaxf(fmaxf(acc[0][k], acc[1][k]), fmaxf(acc[2][k], acc[3][k]));
    hv[k] = valid ? fmaxf(m, 0.0f) : 0.0f;
  }
  int fbase = valid ? (py * 126 + px) : 0;

  int lane = tid & 63, wv = tid >> 6;
#pragma unroll 1
  for (int j = 0; j < 32; j++) {
    const float* wj = fw + (size_t)j * FEAT + fbase;
    float s = hv[0] * wj[0];
#pragma unroll
    for (int k = 1; k < 9; k++) s += hv[k] * wj[k * 15876];
#pragma unroll
    for (int off = 32; off > 0; off >>= 1) s += __shfl_down(s, off);
    if (lane == 0) red[wv][j] = s;
  }
  __syncthreads();
  if (tid < 32) {
    float s = red[0][tid] + red[1][tid] + red[2][tid] + red[3][tid];
    partials[((size_t)b * 64 + blkx) * 32 + tid] = s;
  }
}

// ---------------- warp + alpha composite, head MLP fused in-block ----------------
__global__ __launch_bounds__(256) void warp_kernel(
    const float4* __restrict__ x4,
    const float* __restrict__ partials, // [4][64][32]
    const float* __restrict__ b1,       // [32]
    const float* __restrict__ w2,       // [33][32]
    const float* __restrict__ b2,       // [33]
    const float* __restrict__ w3,       // [66][33]
    const float* __restrict__ b3,       // [66]
    float* __restrict__ out) {
  int bid = blockIdx.x;
  int swz = (bid & 7) * 512 + (bid >> 3);   // 4096 blocks, XCD-chunked
  int b = swz >> 10;
  int t = swz & 1023;
  int ty = t >> 5, tx = t & 31;             // 32x32 tiles of 16x16
  int tid = threadIdx.x;

  __shared__ float h32[32], h33[33], th[66];
  if (tid < 32) {
    float s = b1[tid];
    const float* pb = partials + (size_t)b * 64 * 32 + tid;
    for (int blk = 0; blk < 64; blk++) s += pb[blk * 32];
    h32[tid] = fmaxf(s, 0.0f);
  }
  __syncthreads();
  if (tid < 33) {
    float s = b2[tid];
    for (int j = 0; j < 32; j++) s += h32[j] * w2[tid * 32 + j];
    h33[tid] = fmaxf(s, 0.0f);
  }
  __syncthreads();
  if (tid < 66) {
    float s = b3[tid];
    for (int j2 = 0; j2 < 33; j2++) s += h33[j2] * w3[tid * 33 + j2];
    th[tid] = s;
  }
  __syncthreads();

  if (bid == 0) {
    __shared__ float h32b[128], h33b[132], thb[264];
    for (int u = tid; u < 128; u += 256) {
      int bb = u >> 5, j = u & 31;
      float s = b1[j];
      const float* pb = partials + (size_t)bb * 64 * 32 + j;
      for (int blk = 0; blk < 64; blk++) s += pb[blk * 32];
      h32b[u] = fmaxf(s, 0.0f);
    }
    __syncthreads();
    for (int u = tid; u < 132; u += 256) {
      int bb = u / 33, j2 = u % 33;
      float s = b2[j2];
      for (int j = 0; j < 32; j++) s += h32b[bb * 32 + j] * w2[j2 * 32 + j];
      h33b[u] = fmaxf(s, 0.0f);
    }
    __syncthreads();
    for (int u = tid; u < 264; u += 256) {
      int bb = u / 66, v = u % 66;
      float s = b3[v];
      for (int j2 = 0; j2 < 33; j2++) s += h33b[bb * 33 + j2] * w3[v * 33 + j2];
      thb[u] = s;
    }
    __syncthreads();
    float* out_tail = out + 4194304;
    for (int u = tid; u < 176; u += 256) {
      int bb = u / 44, r = u % 44, p = r / 4, ik = r % 4;
      int i = ik >> 1, k = ik & 1;
      const float* T = &thb[bb * 66 + p * 6];
      out_tail[u] = T[i * 3 + 0] * T[k * 3 + 0] + T[i * 3 + 1] * T[k * 3 + 1];
    }
    for (int u = tid; u < 88; u += 256) {
      int bb = u / 22, r = u % 22, p = r / 2, i = r % 2;
      out_tail[176 + u] = thb[bb * 66 + p * 6 + i * 3 + 2];
    }
  }

  int wvi = tid >> 6, l = tid & 63;
  int y = ty * 16 + wvi * 4 + (l >> 4);
  int x = tx * 16 + (l & 15);
  const float4* img0 = x4 + (size_t)b * 6144 * 512 + 262144;
  float fx = (float)x, fy = (float)y;
  const float cn = (1.0f / 512.0f) - 1.0f;

  float4 v00, v01, v10, v11;
  float wx, wy;
  {
    float T0 = th[0], T1 = th[1], T2 = th[2];
    float T3 = th[3], T4 = th[4], T5 = th[5];
    float Cx = 256.0f * ((T0 + T1) * cn + T2) + 255.5f;
    float Cy = 256.0f * ((T3 + T4) * cn + T5) + 255.5f;
    float ix = fmaf(T0, fx, fmaf(T1, fy, Cx));
    float iy = fmaf(T3, fx, fmaf(T4, fy, Cy));
    float xf = floorf(ix), yf = floorf(iy);
    wx = ix - xf; wy = iy - yf;
    int x0i = min(max((int)xf, 0), 511);
    int x1i = min(max((int)xf + 1, 0), 511);
    int y0i = min(max((int)yf, 0), 511);
    int y1i = min(max((int)yf + 1, 0), 511);
    int off00 = y0i * 512 + x0i;
    int dxs = x1i - x0i, dys = (y1i - y0i) * 512;
    v00 = img0[off00];
    v01 = img0[off00 + dxs];
    v10 = img0[off00 + dys];
    v11 = img0[off00 + dys + dxs];
  }

  float4 stack = make_float4(0.f, 0.f, 0.f, 0.f);
#pragma unroll 1
  for (int i = 0; i < NPARTS; i++) {
    float cwx = wx, cwy = wy;
    float4 c00 = v00, c01 = v01, c10 = v10, c11 = v11;
    if (i + 1 < NPARTS) {
      float T0 = th[(i + 1) * 6 + 0], T1 = th[(i + 1) * 6 + 1], T2 = th[(i + 1) * 6 + 2];
      float T3 = th[(i + 1) * 6 + 3], T4 = th[(i + 1) * 6 + 4], T5 = th[(i + 1) * 6 + 5];
      float Cx = 256.0f * ((T0 + T1) * cn + T2) + 255.5f;
      float Cy = 256.0f * ((T3 + T4) * cn + T5) + 255.5f;
      float ix = fmaf(T0, fx, fmaf(T1, fy, Cx));
      float iy = fmaf(T3, fx, fmaf(T4, fy, Cy));
      float xf = floorf(ix), yf = floorf(iy);
      wx = ix - xf; wy = iy - yf;
      int x0i = min(max((int)xf, 0), 511);
      int x1i = min(max((int)xf + 1, 0), 511);
      int y0i = min(max((int)yf, 0), 511);
      int y1i = min(max((int)yf + 1, 0), 511);
      int off00 = y0i * 512 + x0i;
      int dxs = x1i - x0i, dys = (y1i - y0i) * 512;
      const float4* img = img0 + (size_t)(i + 1) * 262144;
      v00 = img[off00];
      v01 = img[off00 + dxs];
      v10 = img[off00 + dys];
      v11 = img[off00 + dys + dxs];
    }
    float w00 = (1.f - cwx) * (1.f - cwy), w01 = cwx * (1.f - cwy);
    float w10 = (1.f - cwx) * cwy, w11 = cwx * cwy;
    float4 val;
    val.x = c00.x * w00 + c01.x * w01 + c10.x * w10 + c11.x * w11;
    val.y = c00.y * w00 + c01.y * w01 + c10.y * w10 + c11.y * w11;
    val.z = c00.z * w00 + c01.z * w01 + c10.z * w10 + c11.z * w11;
    val.w = c00.w * w00 + c01.w * w01 + c10.w * w10 + c11.w * w11;
    if (i == 0) {
      stack = val;
    } else {
      float a = fminf(fmaxf(val.w, 0.0f), 1.0f);
      stack.x = fminf(fmaxf(stack.x - 2.f * a, -1.f), 1.f);
      stack.y = fminf(fmaxf(stack.y - 2.f * a, -1.f), 1.f);
      stack.z = fminf(fmaxf(stack.z - 2.f * a, -1.f), 1.f);
      stack.w = fminf(fmaxf(stack.w - 2.f * a, -1.f), 1.f);
      stack.x = fminf(fmaxf(stack.x + val.x + 1.f, -1.f), 1.f);
      stack.y = fminf(fmaxf(stack.y + val.y + 1.f, -1.f), 1.f);
      stack.z = fminf(fmaxf(stack.z + val.z + 1.f, -1.f), 1.f);
      stack.w = fminf(fmaxf(stack.w + val.w + 1.f, -1.f), 1.f);
    }
  }
  size_t obase = (size_t)b * 4 * 262144 + (size_t)y * 512 + x;
  out[obase] = stack.x;
  out[obase + 262144] = stack.y;
  out[obase + 2 * 262144] = stack.z;
  out[obase + 3 * 262144] = stack.w;
}

extern "C" void kernel_launch(void* const* d_in, const int* in_sizes, int n_in,
                              void* d_out, int out_size, void* d_ws, size_t ws_size,
                              hipStream_t stream) {
  const float4* x4 = (const float4*)d_in[0];
  const float* conv1_w = (const float*)d_in[1];
  const float* conv1_b = (const float*)d_in[2];
  const float* conv2_w = (const float*)d_in[3];
  const float* conv2_b = (const float*)d_in[4];
  const float* fc1_w = (const float*)d_in[5];
  const float* fc1_b = (const float*)d_in[6];
  const float* fc2_w = (const float*)d_in[7];
  const float* fc2_b = (const float*)d_in[8];
  const float* fc3_w = (const float*)d_in[9];
  const float* fc3_b = (const float*)d_in[10];
  float* ws = (float*)d_ws;
  float* out = (float*)d_out;

  conv1_kernel<<<dim3(512, 4), 128, 0, stream>>>(x4, conv1_w, conv1_b, ws + OFF_H1);
  conv2fc1_kernel<<<dim3(64, 4), 256, 0, stream>>>(ws + OFF_H1, conv2_w, conv2_b,
                                                   fc1_w, ws + OFF_PART);
  warp_kernel<<<4096, 256, 0, stream>>>(x4, ws + OFF_PART, fc1_b, fc2_w, fc2_b,
                                        fc3_w, fc3_b, out);
}